// Round 3
// baseline (103835.327 us; speedup 1.0000x reference)
//
#include <hip/hip_runtime.h>
#include <math.h>

#define BDIM   262144
#define IN_DIM 54
#define HID    256
#define EXPD   512
#define LAT    32
#define NBLK   4
#define NCODES 512
#define EPS    1e-5

// d_out layout (floats): x_recon | z_q_st | indices | commit_loss
#define O_ZQ   14155776
#define O_IDX  22544384
#define O_LOSS 22806528

#define ASTR 258   // a_buf row stride (elements): bank-safe for f64 and f32
#define YSTR 66    // y_buf row stride
#define RSTR 17    // reduction row stride

template<typename T> __device__ __forceinline__ T gelu_T(T x);
template<> __device__ __forceinline__ double gelu_T<double>(double x) {
    return 0.5 * x * (1.0 + erf(x * 0.70710678118654752440));
}
template<> __device__ __forceinline__ float gelu_T<float>(float x) {
    return 0.5f * x * (1.0f + erff(x * 0.70710678f));
}
template<typename T> __device__ __forceinline__ T rsqrt_T(T x);
template<> __device__ __forceinline__ double rsqrt_T<double>(double x) { return 1.0 / sqrt(x); }
template<> __device__ __forceinline__ float  rsqrt_T<float>(float x)  { return 1.0f / sqrtf(x); }

// ---------------------------------------------------------------------------
// LayerNorm phase: acc2 (regs, 16 cols per thread) -> normalized into a_buf.
// If b2 != null, also preloads residual+b2 into acc2 for the FFN accumulate.
// ---------------------------------------------------------------------------
template<typename T>
__device__ __forceinline__ void ln_phase(T acc2[16], T* a_buf, T* red_s, T* red_q,
                                         T* mu_s, T* rs_s,
                                         const float* g, const float* bta,
                                         const float* b2,
                                         int r, int q, int tid)
{
    T s = 0, ss = 0;
    #pragma unroll
    for (int i = 0; i < 16; i++) { T v = acc2[i]; s += v; ss += v * v; }
    red_s[r * RSTR + q] = s; red_q[r * RSTR + q] = ss;
    __syncthreads();
    if (tid < 16) {
        T s2 = 0, ss2 = 0;
        #pragma unroll
        for (int j = 0; j < 16; j++) { s2 += red_s[tid * RSTR + j]; ss2 += red_q[tid * RSTR + j]; }
        T mu = s2 * (T)(1.0 / HID);
        T var = ss2 * (T)(1.0 / HID) - mu * mu;
        mu_s[tid] = mu; rs_s[tid] = rsqrt_T<T>(var + (T)EPS);
    }
    __syncthreads();
    T mu = mu_s[r], rs = rs_s[r];
    #pragma unroll
    for (int i = 0; i < 16; i++) {
        int c = q * 16 + i;
        a_buf[r * ASTR + c] = (acc2[i] - mu) * rs * (T)g[c] + (T)bta[c];
        if (b2) acc2[i] += (T)b2[c];
    }
    __syncthreads();
}

// ---------------------------------------------------------------------------
// FFN: acc2 += gelu(a_buf @ W1 + b1) @ W2   (E chunked by 64 through LDS)
// ---------------------------------------------------------------------------
template<typename T>
__device__ __forceinline__ void mlp_ffn(T acc2[16], const T* a_buf, T* y_buf,
                                        const float* W1, const float* b1,
                                        const float* W2, int r, int q)
{
    for (int e0 = 0; e0 < EXPD; e0 += 64) {
        T y0 = 0, y1 = 0, y2 = 0, y3 = 0;
        const float* w1p = W1 + e0 + q * 4;
        const T* ap = a_buf + r * ASTR;
        #pragma unroll 4
        for (int k = 0; k < HID; k++) {
            T a = ap[k];
            float4 w = *(const float4*)(w1p + (long)k * EXPD);
            y0 += a * (T)w.x; y1 += a * (T)w.y; y2 += a * (T)w.z; y3 += a * (T)w.w;
        }
        int ce = e0 + q * 4;
        y_buf[r * YSTR + q * 4 + 0] = gelu_T<T>(y0 + (T)b1[ce + 0]);
        y_buf[r * YSTR + q * 4 + 1] = gelu_T<T>(y1 + (T)b1[ce + 1]);
        y_buf[r * YSTR + q * 4 + 2] = gelu_T<T>(y2 + (T)b1[ce + 2]);
        y_buf[r * YSTR + q * 4 + 3] = gelu_T<T>(y3 + (T)b1[ce + 3]);
        __syncthreads();
        const float* w2p = W2 + (long)e0 * HID + q * 16;
        #pragma unroll 2
        for (int e = 0; e < 64; e++) {
            T yv = y_buf[r * YSTR + e];
            const float* wr = w2p + (long)e * HID;
            float4 wa = *(const float4*)(wr + 0), wb = *(const float4*)(wr + 4),
                   wc = *(const float4*)(wr + 8), wd = *(const float4*)(wr + 12);
            acc2[0]  += yv * (T)wa.x;  acc2[1]  += yv * (T)wa.y;
            acc2[2]  += yv * (T)wa.z;  acc2[3]  += yv * (T)wa.w;
            acc2[4]  += yv * (T)wb.x;  acc2[5]  += yv * (T)wb.y;
            acc2[6]  += yv * (T)wb.z;  acc2[7]  += yv * (T)wb.w;
            acc2[8]  += yv * (T)wc.x;  acc2[9]  += yv * (T)wc.y;
            acc2[10] += yv * (T)wc.z;  acc2[11] += yv * (T)wc.w;
            acc2[12] += yv * (T)wd.x;  acc2[13] += yv * (T)wd.y;
            acc2[14] += yv * (T)wd.z;  acc2[15] += yv * (T)wd.w;
        }
        __syncthreads();
    }
}

// ---------------------------------------------------------------------------
// Encoder megakernel (f64): x -> proj -> 4 blocks -> LN -> lat -> VQ -> outputs
// 16 rows per workgroup. Zero global scratch.
// ---------------------------------------------------------------------------
__global__ __launch_bounds__(256, 2)
void k_encoder(const float* __restrict__ x,
               const float* __restrict__ epw, const float* __restrict__ epb,
               const float* __restrict__ lng, const float* __restrict__ lnb,
               const float* __restrict__ W1, const float* __restrict__ b1,
               const float* __restrict__ W2, const float* __restrict__ b2,
               const float* __restrict__ ng, const float* __restrict__ nb,
               const float* __restrict__ Wl, const float* __restrict__ bl,
               const float* __restrict__ cb, float* __restrict__ dout)
{
    typedef double T;
    __shared__ T a_buf[16 * ASTR];
    __shared__ T y_buf[16 * YSTR];
    __shared__ T cc_sh[NCODES];
    __shared__ T red_s[16 * RSTR];
    __shared__ T red_q[16 * RSTR];
    __shared__ T mu_s[16], rs_s[16];
    __shared__ int bi_sh[16 * RSTR];
    const int tid = threadIdx.x;
    const int r = tid >> 4, q = tid & 15;
    const long row0 = (long)blockIdx.x * 16;

    // stage x (16 x 54) into y_buf region, stride 56
    {
        T* xs = y_buf;
        #pragma unroll
        for (int j = 0; j < 4; j++) {
            int c = q * 4 + j;
            if (c < IN_DIM) xs[r * 56 + c] = (T)x[(row0 + r) * IN_DIM + c];
        }
    }
    __syncthreads();
    T acc2[16];
    {
        const T* xs = y_buf;
        #pragma unroll
        for (int i = 0; i < 16; i++) acc2[i] = (T)epb[q * 16 + i];
        for (int k = 0; k < IN_DIM; k++) {
            T xv = xs[r * 56 + k];
            const float* wp = epw + (long)k * HID + q * 16;
            float4 wa = *(const float4*)(wp + 0), wb = *(const float4*)(wp + 4),
                   wc = *(const float4*)(wp + 8), wd = *(const float4*)(wp + 12);
            acc2[0]  += xv * (T)wa.x;  acc2[1]  += xv * (T)wa.y;
            acc2[2]  += xv * (T)wa.z;  acc2[3]  += xv * (T)wa.w;
            acc2[4]  += xv * (T)wb.x;  acc2[5]  += xv * (T)wb.y;
            acc2[6]  += xv * (T)wb.z;  acc2[7]  += xv * (T)wb.w;
            acc2[8]  += xv * (T)wc.x;  acc2[9]  += xv * (T)wc.y;
            acc2[10] += xv * (T)wc.z;  acc2[11] += xv * (T)wc.w;
            acc2[12] += xv * (T)wd.x;  acc2[13] += xv * (T)wd.y;
            acc2[14] += xv * (T)wd.z;  acc2[15] += xv * (T)wd.w;
        }
    }
    __syncthreads();

    for (int l = 0; l < NBLK; l++) {
        ln_phase<T>(acc2, a_buf, red_s, red_q, mu_s, rs_s,
                    lng + l * HID, lnb + l * HID, b2 + l * HID, r, q, tid);
        mlp_ffn<T>(acc2, a_buf, y_buf, W1 + (long)l * HID * EXPD, b1 + l * EXPD,
                   W2 + (long)l * EXPD * HID, r, q);
    }
    // final encoder LN (no residual preload)
    ln_phase<T>(acc2, a_buf, red_s, red_q, mu_s, rs_s, ng, nb, nullptr, r, q, tid);

    // latent projection -> zbuf (y_buf region, stride 34)
    {
        T* zbuf = y_buf;
        int j0 = q * 2;
        T z0 = (T)bl[j0], z1 = (T)bl[j0 + 1];
        const T* ap = a_buf + r * ASTR;
        #pragma unroll 4
        for (int k = 0; k < HID; k++) {
            T a = ap[k];
            float2 w = *(const float2*)(Wl + (long)k * LAT + j0);
            z0 += a * (T)w.x; z1 += a * (T)w.y;
        }
        zbuf[r * 34 + j0] = z0; zbuf[r * 34 + j0 + 1] = z1;
    }
    // codebook squared norms (once per block)
    #pragma unroll
    for (int u = 0; u < 2; u++) {
        int c = tid * 2 + u;
        const float* cp = cb + (long)c * LAT;
        T sc = 0;
        #pragma unroll
        for (int j = 0; j < LAT; j += 4) {
            float4 v = *(const float4*)(cp + j);
            sc += (T)v.x * (T)v.x + (T)v.y * (T)v.y + (T)v.z * (T)v.z + (T)v.w * (T)v.w;
        }
        cc_sh[c] = sc;
    }
    __syncthreads();
    // VQ scan: thread (r,q) scans codes q*32 .. q*32+31 for row r
    {
        const T* zbuf = y_buf;
        T zr[32];
        #pragma unroll
        for (int j = 0; j < LAT; j++) zr[j] = zbuf[r * 34 + j];
        T zz = 0;
        #pragma unroll
        for (int j = 0; j < LAT; j++) zz += zr[j] * zr[j];
        T bd = (T)1e300; int bi = 0;
        for (int c = 0; c < 32; c++) {
            int code = q * 32 + c;
            const float* cp = cb + (long)code * LAT;
            T dot = 0;
            #pragma unroll
            for (int j = 0; j < LAT; j += 4) {
                float4 v = *(const float4*)(cp + j);
                dot += zr[j] * (T)v.x + zr[j + 1] * (T)v.y
                     + zr[j + 2] * (T)v.z + zr[j + 3] * (T)v.w;
            }
            T d2 = (zz - 2.0 * dot) + cc_sh[code];
            if (d2 < bd) { bd = d2; bi = code; }   // strict <: first-min, matches np.argmin
        }
        red_s[r * RSTR + q] = bd;
        bi_sh[r * RSTR + q] = bi;
    }
    __syncthreads();
    if (tid < 16) {
        T bd = red_s[tid * RSTR + 0]; int bi = bi_sh[tid * RSTR + 0];
        #pragma unroll
        for (int j = 1; j < 16; j++) {
            T v = red_s[tid * RSTR + j];
            if (v < bd) { bd = v; bi = bi_sh[tid * RSTR + j]; }  // ascending q: ties keep smaller idx
        }
        long grow = row0 + tid;
        dout[O_IDX + grow] = (float)bi;
        const float* cq = cb + (long)bi * LAT;
        #pragma unroll 8
        for (int j = 0; j < LAT; j++) dout[O_ZQ + grow * LAT + j] = cq[j];
        red_q[tid] = bd;
    }
    __syncthreads();
    if (tid == 0) {
        T t = 0;
        #pragma unroll
        for (int i = 0; i < 16; i++) t += red_q[i];
        atomicAdd(&dout[O_LOSS], (float)t);
    }
}

// ---------------------------------------------------------------------------
// Decoder megakernel (f32): z_q -> lat -> 4 blocks -> LN -> proj -> x_recon
// ---------------------------------------------------------------------------
__global__ __launch_bounds__(256, 2)
void k_decoder(float* __restrict__ dout,
               const float* __restrict__ Wl, const float* __restrict__ bl,
               const float* __restrict__ lng, const float* __restrict__ lnb,
               const float* __restrict__ W1, const float* __restrict__ b1,
               const float* __restrict__ W2, const float* __restrict__ b2,
               const float* __restrict__ ng, const float* __restrict__ nb,
               const float* __restrict__ Wp, const float* __restrict__ pb)
{
    typedef float T;
    __shared__ T a_buf[16 * ASTR];
    __shared__ T y_buf[16 * YSTR];
    __shared__ T red_s[16 * RSTR];
    __shared__ T red_q[16 * RSTR];
    __shared__ T mu_s[16], rs_s[16];
    const int tid = threadIdx.x;
    const int r = tid >> 4, q = tid & 15;
    const long row0 = (long)blockIdx.x * 16;

    // stage z_q (16 x 32) into y_buf, stride 34
    {
        T* zq = y_buf;
        float2 v = *(const float2*)(dout + O_ZQ + (row0 + r) * LAT + q * 2);
        zq[r * 34 + q * 2] = v.x; zq[r * 34 + q * 2 + 1] = v.y;
    }
    __syncthreads();
    T acc2[16];
    {
        const T* zq = y_buf;
        #pragma unroll
        for (int i = 0; i < 16; i++) acc2[i] = bl[q * 16 + i];
        #pragma unroll 4
        for (int k = 0; k < LAT; k++) {
            T xv = zq[r * 34 + k];
            const float* wp = Wl + (long)k * HID + q * 16;
            float4 wa = *(const float4*)(wp + 0), wb = *(const float4*)(wp + 4),
                   wc = *(const float4*)(wp + 8), wd = *(const float4*)(wp + 12);
            acc2[0]  += xv * wa.x;  acc2[1]  += xv * wa.y;
            acc2[2]  += xv * wa.z;  acc2[3]  += xv * wa.w;
            acc2[4]  += xv * wb.x;  acc2[5]  += xv * wb.y;
            acc2[6]  += xv * wb.z;  acc2[7]  += xv * wb.w;
            acc2[8]  += xv * wc.x;  acc2[9]  += xv * wc.y;
            acc2[10] += xv * wc.z;  acc2[11] += xv * wc.w;
            acc2[12] += xv * wd.x;  acc2[13] += xv * wd.y;
            acc2[14] += xv * wd.z;  acc2[15] += xv * wd.w;
        }
    }
    __syncthreads();
    for (int l = 0; l < NBLK; l++) {
        ln_phase<T>(acc2, a_buf, red_s, red_q, mu_s, rs_s,
                    lng + l * HID, lnb + l * HID, b2 + l * HID, r, q, tid);
        mlp_ffn<T>(acc2, a_buf, y_buf, W1 + (long)l * HID * EXPD, b1 + l * EXPD,
                   W2 + (long)l * EXPD * HID, r, q);
    }
    ln_phase<T>(acc2, a_buf, red_s, red_q, mu_s, rs_s, ng, nb, nullptr, r, q, tid);

    // output projection: cols q*4+j (guard < 54)
    const T* ap = a_buf + r * ASTR;
    #pragma unroll
    for (int j = 0; j < 4; j++) {
        int c = q * 4 + j;
        if (c < IN_DIM) {
            T acc = pb[c];
            #pragma unroll 4
            for (int k = 0; k < HID; k++)
                acc += ap[k] * Wp[(long)k * IN_DIM + c];
            dout[(row0 + r) * IN_DIM + c] = acc;
        }
    }
}

__global__ void k_zero(float* p) { *p = 0.0f; }
__global__ void k_final(float* p) { *p = *p * (1.0f / 8388608.0f); }  // / (B*LAT) = 2^-23, exact

// ---------------------------------------------------------------------------
extern "C" void kernel_launch(void* const* d_in, const int* in_sizes, int n_in,
                              void* d_out, int out_size, void* d_ws, size_t ws_size,
                              hipStream_t stream)
{
    (void)in_sizes; (void)n_in; (void)out_size; (void)d_ws; (void)ws_size;
    const float* x     = (const float*)d_in[0];
    const float* epw   = (const float*)d_in[1];
    const float* epb   = (const float*)d_in[2];
    const float* elng  = (const float*)d_in[3];
    const float* elnb  = (const float*)d_in[4];
    const float* ew1   = (const float*)d_in[5];
    const float* eb1   = (const float*)d_in[6];
    const float* ew2   = (const float*)d_in[7];
    const float* eb2   = (const float*)d_in[8];
    const float* eng   = (const float*)d_in[9];
    const float* enb   = (const float*)d_in[10];
    const float* elatw = (const float*)d_in[11];
    const float* elatb = (const float*)d_in[12];
    const float* cbk   = (const float*)d_in[13];
    const float* dlatw = (const float*)d_in[14];
    const float* dlatb = (const float*)d_in[15];
    const float* dlng  = (const float*)d_in[16];
    const float* dlnb  = (const float*)d_in[17];
    const float* dw1   = (const float*)d_in[18];
    const float* db1   = (const float*)d_in[19];
    const float* dw2   = (const float*)d_in[20];
    const float* db2   = (const float*)d_in[21];
    const float* dng   = (const float*)d_in[22];
    const float* dnb   = (const float*)d_in[23];
    const float* dpw   = (const float*)d_in[24];
    const float* dpb   = (const float*)d_in[25];
    float* out = (float*)d_out;

    dim3 blk(256, 1, 1);
    k_zero<<<1, 1, 0, stream>>>(out + O_LOSS);
    k_encoder<<<BDIM / 16, blk, 0, stream>>>(
        x, epw, epb, elng, elnb, ew1, eb1, ew2, eb2, eng, enb, elatw, elatb, cbk, out);
    k_decoder<<<BDIM / 16, blk, 0, stream>>>(
        out, dlatw, dlatb, dlng, dlnb, dw1, db1, dw2, db2, dng, dnb, dpw, dpb);
    k_final<<<1, 1, 0, stream>>>(out + O_LOSS);
}

// Round 4
// 44818.414 us; speedup vs baseline: 2.3168x; 2.3168x over previous
//
#include <hip/hip_runtime.h>
#include <math.h>

#define BDIM   262144
#define IN_DIM 54
#define HID    256
#define EXPD   512
#define LAT    32
#define NBLK   4
#define NCODES 512
#define EPS    1e-5

// d_out layout (floats): x_recon | z_q_st | indices | commit_loss
#define O_ZQ   14155776
#define O_IDX  22544384
#define O_LOSS 22806528

// smem layout (bytes):
//   r0 [0,16384):      aT / y_halfT / xT / zqT   ([k][16] f32, transposed)
//   r1 [16384,49152):  weight slabs / Wl / dpw chunks
//   enc extra [49152,57600): zbuf (16*34 f64) | ccs (512 f64)

template<typename T> __device__ __forceinline__ T gelu_T(T x);
template<> __device__ __forceinline__ double gelu_T<double>(double x) {
    return 0.5 * x * (1.0 + erf(x * 0.70710678118654752440));
}
template<> __device__ __forceinline__ float gelu_T<float>(float x) {
    return 0.5f * x * (1.0f + erff(x * 0.70710678f));
}
template<typename T> __device__ __forceinline__ T rsqrt_T(T x);
template<> __device__ __forceinline__ double rsqrt_T<double>(double x) { return 1.0 / sqrt(x); }
template<> __device__ __forceinline__ float  rsqrt_T<float>(float x)  { return 1.0f / sqrtf(x); }

// ---------------------------------------------------------------------------
// LayerNorm: acc[4][4] regs (row rt*4+i, col ct*4+j) -> normalized f32 into
// r0 transposed [c][16]. Wave-local shfl reduction (each wave owns 4 rows).
// If b2 != null, preload residual bias into acc for the FFN accumulate.
// ---------------------------------------------------------------------------
template<typename T>
__device__ __forceinline__ void ln_to_abuf(T acc[4][4], float* r0,
    const float* __restrict__ g, const float* __restrict__ bta,
    const float* __restrict__ b2, int rt, int ct)
{
    T s[4], sq[4];
    #pragma unroll
    for (int i = 0; i < 4; i++) {
        s[i]  = acc[i][0] + acc[i][1] + acc[i][2] + acc[i][3];
        sq[i] = acc[i][0]*acc[i][0] + acc[i][1]*acc[i][1]
              + acc[i][2]*acc[i][2] + acc[i][3]*acc[i][3];
    }
    #pragma unroll
    for (int m = 1; m < 64; m <<= 1) {
        #pragma unroll
        for (int i = 0; i < 4; i++) {
            s[i]  += __shfl_xor(s[i],  m);
            sq[i] += __shfl_xor(sq[i], m);
        }
    }
    float4 gv = *(const float4*)(g + ct*4);
    float4 bv = *(const float4*)(bta + ct*4);
    float gj[4] = {gv.x, gv.y, gv.z, gv.w};
    float bj[4] = {bv.x, bv.y, bv.z, bv.w};
    #pragma unroll
    for (int i = 0; i < 4; i++) {
        T mu  = s[i]  * (T)(1.0 / HID);
        T var = sq[i] * (T)(1.0 / HID) - mu * mu;
        T rs  = rsqrt_T<T>(var + (T)EPS);
        #pragma unroll
        for (int j = 0; j < 4; j++)
            r0[(ct*4 + j)*16 + rt*4 + i] = (float)((acc[i][j] - mu) * rs * (T)gj[j] + (T)bj[j]);
    }
    if (b2) {
        float4 b2v = *(const float4*)(b2 + ct*4);
        float bb[4] = {b2v.x, b2v.y, b2v.z, b2v.w};
        #pragma unroll
        for (int i = 0; i < 4; i++)
            #pragma unroll
            for (int j = 0; j < 4; j++)
                acc[i][j] += (T)bb[j];
    }
}

// ---------------------------------------------------------------------------
// GEMM1: yacc[16 rows x 512 cols tile] = aT[256][16] @ W1[256][512]
// k-slabs of 16 rows (32KB) staged via register relay; thread tile 4x8
// (cols ct*4..+3 and 256+ct*4..+3).
// ---------------------------------------------------------------------------
template<typename T>
__device__ __forceinline__ void ffn_gemm1(T yacc[4][8], const float* __restrict__ W1,
                                          const float* r0, float* r1,
                                          int rt, int ct, int tid)
{
    #pragma unroll
    for (int i = 0; i < 4; i++)
        #pragma unroll
        for (int j = 0; j < 8; j++) yacc[i][j] = 0;
    float4 R[8];
    #pragma unroll
    for (int u = 0; u < 8; u++) R[u] = *(const float4*)(W1 + (tid + 256*u)*4);
    for (int k0 = 0; k0 < HID; k0 += 16) {
        #pragma unroll
        for (int u = 0; u < 8; u++) *(float4*)(r1 + (tid + 256*u)*4) = R[u];
        __syncthreads();
        if (k0 + 16 < HID) {
            const float* src = W1 + (long)(k0 + 16) * EXPD;
            #pragma unroll
            for (int u = 0; u < 8; u++) R[u] = *(const float4*)(src + (tid + 256*u)*4);
        }
        #pragma unroll 2
        for (int k = 0; k < 16; k++) {
            float4 av = *(const float4*)(r0 + (k0 + k)*16 + rt*4);      // broadcast
            float4 w0 = *(const float4*)(r1 + k*EXPD + ct*4);           // contiguous
            float4 w1 = *(const float4*)(r1 + k*EXPD + 256 + ct*4);
            T a[4]  = {(T)av.x, (T)av.y, (T)av.z, (T)av.w};
            T wv[8] = {(T)w0.x, (T)w0.y, (T)w0.z, (T)w0.w,
                       (T)w1.x, (T)w1.y, (T)w1.z, (T)w1.w};
            #pragma unroll
            for (int i = 0; i < 4; i++)
                #pragma unroll
                for (int j = 0; j < 8; j++)
                    yacc[i][j] += a[i] * wv[j];
        }
        __syncthreads();
    }
}

// ---------------------------------------------------------------------------
// GEMM2-style accumulate: acc[4][4] += aT[E][16] @ W[E][256]
// e-slabs of 32 rows (32KB) staged via register relay; thread tile 4x4.
// Used for FFN-GEMM2 halves (E=256), enc entry (E=54), dec entry (E=32).
// ---------------------------------------------------------------------------
template<typename T>
__device__ __forceinline__ void gemm2_acc(T acc[4][4], const float* __restrict__ W, int E,
                                          const float* r0, float* r1,
                                          int rt, int ct, int tid)
{
    float4 R[8];
    {
        int n0 = (E < 32 ? E : 32) * 64;
        #pragma unroll
        for (int u = 0; u < 8; u++) {
            int idx = tid + 256*u;
            if (idx < n0) R[u] = *(const float4*)(W + idx*4);
        }
    }
    for (int e0 = 0; e0 < E; e0 += 32) {
        int n = E - e0; if (n > 32) n = 32;
        #pragma unroll
        for (int u = 0; u < 8; u++) {
            int idx = tid + 256*u;
            if (idx < n*64) *(float4*)(r1 + idx*4) = R[u];
        }
        __syncthreads();
        if (e0 + 32 < E) {
            int n2 = E - e0 - 32; if (n2 > 32) n2 = 32;
            const float* src = W + (long)(e0 + 32) * HID;
            #pragma unroll
            for (int u = 0; u < 8; u++) {
                int idx = tid + 256*u;
                if (idx < n2*64) R[u] = *(const float4*)(src + idx*4);
            }
        }
        #pragma unroll 2
        for (int e = 0; e < n; e++) {
            float4 av = *(const float4*)(r0 + (e0 + e)*16 + rt*4);      // broadcast
            float4 wv = *(const float4*)(r1 + e*HID + ct*4);            // contiguous
            T a[4] = {(T)av.x, (T)av.y, (T)av.z, (T)av.w};
            T w[4] = {(T)wv.x, (T)wv.y, (T)wv.z, (T)wv.w};
            #pragma unroll
            for (int i = 0; i < 4; i++)
                #pragma unroll
                for (int j = 0; j < 4; j++)
                    acc[i][j] += a[i] * w[j];
        }
        __syncthreads();
    }
}

// ---------------------------------------------------------------------------
// One residual FFN block: acc = acc + gelu(LN(acc) @ W1 + b1) @ W2 + b2
// ---------------------------------------------------------------------------
template<typename T>
__device__ __forceinline__ void ffn_layer(T acc[4][4], float* r0, float* r1,
    const float* lng, const float* lnb,
    const float* W1, const float* b1, const float* W2, const float* b2,
    int rt, int ct, int tid)
{
    ln_to_abuf<T>(acc, r0, lng, lnb, b2, rt, ct);
    T yacc[4][8];
    ffn_gemm1<T>(yacc, W1, r0, r1, rt, ct, tid);   // ends with barrier
    #pragma unroll
    for (int h = 0; h < 2; h++) {
        float4 b1v = *(const float4*)(b1 + h*256 + ct*4);
        float bb[4] = {b1v.x, b1v.y, b1v.z, b1v.w};
        #pragma unroll
        for (int i = 0; i < 4; i++)
            #pragma unroll
            for (int j = 0; j < 4; j++)
                r0[(ct*4 + j)*16 + rt*4 + i] =
                    (float)gelu_T<T>(yacc[i][h*4 + j] + (T)bb[j]);
        gemm2_acc<T>(acc, W2 + (long)h*256*HID, 256, r0, r1, rt, ct, tid);
    }
}

// ---------------------------------------------------------------------------
// Encoder megakernel (f64 acc, f32 LDS storage)
// ---------------------------------------------------------------------------
__global__ __launch_bounds__(256)
void k_encoder(const float* __restrict__ x,
               const float* __restrict__ epw, const float* __restrict__ epb,
               const float* __restrict__ lng, const float* __restrict__ lnb,
               const float* __restrict__ W1, const float* __restrict__ b1,
               const float* __restrict__ W2, const float* __restrict__ b2,
               const float* __restrict__ ng, const float* __restrict__ nb,
               const float* __restrict__ Wl, const float* __restrict__ bl,
               const float* __restrict__ cb, float* __restrict__ dout)
{
    typedef double T;
    __shared__ __align__(16) char smem[57600];
    float*  r0   = (float*)smem;
    float*  r1   = (float*)(smem + 16384);
    double* zbuf = (double*)(smem + 49152);
    double* ccs  = (double*)(smem + 53504);
    const int tid = threadIdx.x;
    const int rt = tid >> 6, ct = tid & 63;
    const long row0 = (long)blockIdx.x * 16;

    // stage xT [54][16]
    #pragma unroll
    for (int u = 0; u < 4; u++) {
        int idx = tid + 256*u;
        if (idx < 16 * IN_DIM) {
            int r = idx / IN_DIM, c = idx % IN_DIM;
            r0[c*16 + r] = x[(row0 + r)*IN_DIM + c];
        }
    }
    T acc[4][4];
    {
        float4 bv = *(const float4*)(epb + ct*4);
        float bb[4] = {bv.x, bv.y, bv.z, bv.w};
        #pragma unroll
        for (int i = 0; i < 4; i++)
            #pragma unroll
            for (int j = 0; j < 4; j++) acc[i][j] = (T)bb[j];
    }
    gemm2_acc<T>(acc, epw, IN_DIM, r0, r1, rt, ct, tid);

    for (int l = 0; l < NBLK; l++)
        ffn_layer<T>(acc, r0, r1, lng + l*HID, lnb + l*HID,
                     W1 + (long)l*HID*EXPD, b1 + l*EXPD,
                     W2 + (long)l*EXPD*HID, b2 + l*HID, rt, ct, tid);

    // final encoder LN
    ln_to_abuf<T>(acc, r0, ng, nb, nullptr, rt, ct);
    // stage Wl [256][32] into r1 (32KB); codebook norms into ccs
    #pragma unroll
    for (int u = 0; u < 8; u++)
        *(float4*)(r1 + (tid + 256*u)*4) = *(const float4*)(Wl + (tid + 256*u)*4);
    #pragma unroll
    for (int u = 0; u < 2; u++) {
        int c = tid*2 + u;
        const float* cp = cb + (long)c * LAT;
        T sc = 0;
        #pragma unroll
        for (int j = 0; j < LAT; j += 4) {
            float4 v = *(const float4*)(cp + j);
            sc += (T)v.x*(T)v.x + (T)v.y*(T)v.y + (T)v.z*(T)v.z + (T)v.w*(T)v.w;
        }
        ccs[c] = sc;
    }
    __syncthreads();

    // latent projection, (r,q) map
    const int r = tid >> 4, q = tid & 15;
    {
        float2 blv = *(const float2*)(bl + q*2);
        T z0 = (T)blv.x, z1 = (T)blv.y;
        #pragma unroll 4
        for (int k = 0; k < HID; k++) {
            T a = (T)r0[k*16 + r];                       // broadcast
            float2 w = *(const float2*)(r1 + k*LAT + q*2);
            z0 += a * (T)w.x; z1 += a * (T)w.y;
        }
        zbuf[r*34 + q*2] = z0; zbuf[r*34 + q*2 + 1] = z1;
    }
    __syncthreads();

    // VQ: thread (r,q) scans codes q*32..q*32+31
    T bd; int bi;
    {
        T zr[32];
        #pragma unroll
        for (int j = 0; j < LAT; j++) zr[j] = zbuf[r*34 + j];
        T zz = 0;
        #pragma unroll
        for (int j = 0; j < LAT; j++) zz += zr[j]*zr[j];
        bd = (T)1e300; bi = 0;
        for (int c0 = 0; c0 < 32; c0++) {
            int code = q*32 + c0;
            const float* cp = cb + (long)code * LAT;
            T dot = 0;
            #pragma unroll
            for (int j = 0; j < LAT; j += 4) {
                float4 v = *(const float4*)(cp + j);
                dot += zr[j]*(T)v.x + zr[j+1]*(T)v.y + zr[j+2]*(T)v.z + zr[j+3]*(T)v.w;
            }
            T d2 = (zz - 2.0*dot) + ccs[code];
            if (d2 < bd) { bd = d2; bi = code; }         // strict <: first-min
        }
        #pragma unroll
        for (int m = 1; m < 16; m <<= 1) {
            T ob = __shfl_xor(bd, m);
            int obi = __shfl_xor(bi, m);
            if (ob < bd || (ob == bd && obi < bi)) { bd = ob; bi = obi; }
        }
        if (q == 0) {
            long grow = row0 + r;
            dout[O_IDX + grow] = (float)bi;
            const float* cq = cb + (long)bi * LAT;
            #pragma unroll
            for (int j = 0; j < LAT; j += 4)
                *(float4*)(dout + O_ZQ + grow*LAT + j) = *(const float4*)(cq + j);
        }
    }
    // commit loss: wave sums -> block sum -> one atomic
    __syncthreads();                   // zbuf free for reuse
    T ws = bd;
    ws += __shfl_xor(ws, 16);
    ws += __shfl_xor(ws, 32);
    if ((tid & 63) == 0) zbuf[tid >> 6] = ws;
    __syncthreads();
    if (tid == 0)
        atomicAdd(dout + O_LOSS, (float)(zbuf[0] + zbuf[1] + zbuf[2] + zbuf[3]));
}

// ---------------------------------------------------------------------------
// Decoder megakernel (f32)
// ---------------------------------------------------------------------------
__global__ __launch_bounds__(256)
void k_decoder(float* __restrict__ dout,
               const float* __restrict__ Wl, const float* __restrict__ bl,
               const float* __restrict__ lng, const float* __restrict__ lnb,
               const float* __restrict__ W1, const float* __restrict__ b1,
               const float* __restrict__ W2, const float* __restrict__ b2,
               const float* __restrict__ ng, const float* __restrict__ nb,
               const float* __restrict__ Wp, const float* __restrict__ pb)
{
    typedef float T;
    __shared__ __align__(16) char smem[49152];
    float* r0 = (float*)smem;
    float* r1 = (float*)(smem + 16384);
    const int tid = threadIdx.x;
    const int rt = tid >> 6, ct = tid & 63;
    const long row0 = (long)blockIdx.x * 16;

    // stage zqT [32][16]
    #pragma unroll
    for (int u = 0; u < 2; u++) {
        int idx = tid + 256*u;                 // < 512
        int r = idx >> 5, c = idx & 31;
        r0[c*16 + r] = dout[O_ZQ + (row0 + r)*LAT + c];
    }
    T acc[4][4];
    {
        float4 bv = *(const float4*)(bl + ct*4);
        float bb[4] = {bv.x, bv.y, bv.z, bv.w};
        #pragma unroll
        for (int i = 0; i < 4; i++)
            #pragma unroll
            for (int j = 0; j < 4; j++) acc[i][j] = bb[j];
    }
    gemm2_acc<T>(acc, Wl, LAT, r0, r1, rt, ct, tid);

    for (int l = 0; l < NBLK; l++)
        ffn_layer<T>(acc, r0, r1, lng + l*HID, lnb + l*HID,
                     W1 + (long)l*HID*EXPD, b1 + l*EXPD,
                     W2 + (long)l*EXPD*HID, b2 + l*HID, rt, ct, tid);

    ln_to_abuf<T>(acc, r0, ng, nb, nullptr, rt, ct);

    // output projection, (r,q) map; dpw staged in 2 k-chunks of 128
    const int r = tid >> 4, q = tid & 15;
    float oacc[4];
    #pragma unroll
    for (int j = 0; j < 4; j++) {
        int c = q*4 + j;
        oacc[j] = (c < IN_DIM) ? pb[c] : 0.f;
    }
    for (int k0 = 0; k0 < HID; k0 += 128) {
        #pragma unroll
        for (int u = 0; u < 7; u++) {
            int idx = tid + 256*u;
            if (idx < 1728)                   // 128*54/4 float4s
                ((float4*)r1)[idx] = ((const float4*)(Wp + (long)k0*IN_DIM))[idx];
        }
        __syncthreads();
        #pragma unroll 4
        for (int k = 0; k < 128; k++) {
            float a = r0[(k0 + k)*16 + r];    // broadcast
            #pragma unroll
            for (int j = 0; j < 4; j++)
                oacc[j] += a * r1[k*IN_DIM + q*4 + j];   // may read pad garbage for c>=54
        }
        __syncthreads();
    }
    #pragma unroll
    for (int j = 0; j < 4; j++) {
        int c = q*4 + j;
        if (c < IN_DIM) dout[(row0 + r)*IN_DIM + c] = oacc[j];
    }
}

__global__ void k_zero(float* p) { *p = 0.0f; }
__global__ void k_final(float* p) { *p = *p * (1.0f / 8388608.0f); }  // / (B*LAT) = 2^-23, exact

// ---------------------------------------------------------------------------
extern "C" void kernel_launch(void* const* d_in, const int* in_sizes, int n_in,
                              void* d_out, int out_size, void* d_ws, size_t ws_size,
                              hipStream_t stream)
{
    (void)in_sizes; (void)n_in; (void)out_size; (void)d_ws; (void)ws_size;
    const float* x     = (const float*)d_in[0];
    const float* epw   = (const float*)d_in[1];
    const float* epb   = (const float*)d_in[2];
    const float* elng  = (const float*)d_in[3];
    const float* elnb  = (const float*)d_in[4];
    const float* ew1   = (const float*)d_in[5];
    const float* eb1   = (const float*)d_in[6];
    const float* ew2   = (const float*)d_in[7];
    const float* eb2   = (const float*)d_in[8];
    const float* eng   = (const float*)d_in[9];
    const float* enb   = (const float*)d_in[10];
    const float* elatw = (const float*)d_in[11];
    const float* elatb = (const float*)d_in[12];
    const float* cbk   = (const float*)d_in[13];
    const float* dlatw = (const float*)d_in[14];
    const float* dlatb = (const float*)d_in[15];
    const float* dlng  = (const float*)d_in[16];
    const float* dlnb  = (const float*)d_in[17];
    const float* dw1   = (const float*)d_in[18];
    const float* db1   = (const float*)d_in[19];
    const float* dw2   = (const float*)d_in[20];
    const float* db2   = (const float*)d_in[21];
    const float* dng   = (const float*)d_in[22];
    const float* dnb   = (const float*)d_in[23];
    const float* dpw   = (const float*)d_in[24];
    const float* dpb   = (const float*)d_in[25];
    float* out = (float*)d_out;

    dim3 blk(256, 1, 1);
    k_zero<<<1, 1, 0, stream>>>(out + O_LOSS);
    k_encoder<<<BDIM / 16, blk, 0, stream>>>(
        x, epw, epb, elng, elnb, ew1, eb1, ew2, eb2, eng, enb, elatw, elatb, cbk, out);
    k_decoder<<<BDIM / 16, blk, 0, stream>>>(
        out, dlatw, dlatb, dlng, dlnb, dw1, db1, dw2, db2, dng, dnb, dpw, dpb);
    k_final<<<1, 1, 0, stream>>>(out + O_LOSS);
}